// Round 1
// baseline (112.314 us; speedup 1.0000x reference)
//
#include <hip/hip_runtime.h>
#include <hip/hip_bf16.h>

// out[b,o,n] = sum_h W[n,o,h] * x[b,h,n] + bias[n,o]
// x: [16][32][50000] f32, W: [50000][32][32] f32, bias: [50000][32] f32
// out: [16][32][50000] f32

#define NT 16          // nodes per block
#define NNODES 50000
#define BATCH 16
#define CH 32

__global__ __launch_bounds__(256, 4)
void localconv1d_kernel(const float* __restrict__ x,
                        const float* __restrict__ W,
                        const float* __restrict__ bias,
                        float* __restrict__ out) {
    // x tile in LDS: [b][h][nn]  (nn fastest -> broadcast-friendly reads)
    __shared__ float xs[BATCH * CH * NT];   // 32 KB

    const int tid = threadIdx.x;
    const int n0  = blockIdx.x * NT;

    // ---- stage x tile: 16*32*16 = 8192 floats = 2048 float4, 256 threads * 8 ----
    #pragma unroll
    for (int k = 0; k < 8; ++k) {
        int idx = k * 256 + tid;      // 0..2047
        int row = idx >> 2;           // b*32+h, 0..511
        int c4  = idx & 3;            // which float4 within the 16-node row
        float4 v = *reinterpret_cast<const float4*>(
            x + (size_t)row * NNODES + n0 + c4 * 4);
        *reinterpret_cast<float4*>(&xs[row * NT + c4 * 4]) = v;
    }
    __syncthreads();

    // ---- each thread: one node nn, two out-channels (og, og+16), all 16 batches ----
    const int nn = tid & (NT - 1);
    const int og = tid >> 4;          // 0..15
    const int n  = n0 + nn;
    const int o0 = og;
    const int o1 = og + 16;

    // weights for the two output channels: 2 * 32 floats, per-lane contiguous
    float4 w0[8], w1[8];
    const float4* W0 = reinterpret_cast<const float4*>(W + ((size_t)n * CH + o0) * CH);
    const float4* W1 = reinterpret_cast<const float4*>(W + ((size_t)n * CH + o1) * CH);
    #pragma unroll
    for (int k = 0; k < 8; ++k) { w0[k] = W0[k]; w1[k] = W1[k]; }

    const float b0 = bias[(size_t)n * CH + o0];
    const float b1 = bias[(size_t)n * CH + o1];

    #pragma unroll
    for (int b = 0; b < BATCH; ++b) {
        float a0 = b0, a1 = b1;
        const float* xb = &xs[(b * CH) * NT + nn];
        #pragma unroll
        for (int h4 = 0; h4 < 8; ++h4) {
            const float* w0p = reinterpret_cast<const float*>(&w0[h4]);
            const float* w1p = reinterpret_cast<const float*>(&w1[h4]);
            #pragma unroll
            for (int j = 0; j < 4; ++j) {
                float xv = xb[(h4 * 4 + j) * NT];
                a0 = fmaf(w0p[j], xv, a0);
                a1 = fmaf(w1p[j], xv, a1);
            }
        }
        out[((size_t)b * CH + o0) * NNODES + n] = a0;
        out[((size_t)b * CH + o1) * NNODES + n] = a1;
    }
}

extern "C" void kernel_launch(void* const* d_in, const int* in_sizes, int n_in,
                              void* d_out, int out_size, void* d_ws, size_t ws_size,
                              hipStream_t stream) {
    const float* x    = (const float*)d_in[0];
    const float* W    = (const float*)d_in[1];
    const float* bias = (const float*)d_in[2];
    float* out        = (float*)d_out;

    const int blocks = NNODES / NT;   // 50000/16 = 3125
    localconv1d_kernel<<<blocks, 256, 0, stream>>>(x, W, bias, out);
}

// Round 2
// 110.003 us; speedup vs baseline: 1.0210x; 1.0210x over previous
//
#include <hip/hip_runtime.h>

// out[b,o,n] = sum_h W[n,o,h] * x[b,h,n] + bias[n,o]
// x: [16][32][50000] f32, W: [50000][32][32] f32, bias: [50000][32] f32

#define NT 32          // nodes per block
#define NN 50000
#define BATCH 16
#define CH 32
#define TPB 512

typedef float __attribute__((address_space(1))) gfloat_t;
typedef float __attribute__((address_space(3))) lfloat_t;

__global__ __launch_bounds__(TPB, 4)   // 4 waves/EU = 2 blocks/CU, VGPR cap 128
void localconv1d_kernel(const float* __restrict__ x,
                        const float* __restrict__ W,
                        const float* __restrict__ bias,
                        float* __restrict__ out) {
    // x tile: [b][h][nn], nn fastest (broadcast-friendly LDS reads)
    __shared__ float xs[BATCH * CH * NT];   // 64 KB

    const int tid = threadIdx.x;
    const int n0  = blockIdx.x * NT;
    const int nn  = tid & (NT - 1);
    const int og  = tid >> 5;            // 0..15
    const int n   = n0 + nn;
    const bool valid = (n < NN);
    const int nc = valid ? n : (NN - 1);  // clamped for loads

    // ---- issue x staging loads (direct global->LDS, stays in flight) ----
    if (n0 + NT <= NN) {
        #pragma unroll
        for (int k = 0; k < 8; ++k) {
            int idx = k * TPB + tid;     // 0..4095
            int row = idx >> 3;          // b*32+h, 0..511
            int c4  = idx & 7;           // float4 index within 32-node row
            __builtin_amdgcn_global_load_lds(
                (const gfloat_t*)(x + (size_t)row * NN + n0 + c4 * 4),
                (lfloat_t*)(&xs[idx * 4]),
                16, 0, 0);
        }
    } else {
        // tail block: guarded reg staging (nodes valid count is multiple of 16,
        // so float4s are either fully valid or fully out of range)
        #pragma unroll
        for (int k = 0; k < 8; ++k) {
            int idx = k * TPB + tid;
            int row = idx >> 3;
            int c4  = idx & 7;
            float4 v = make_float4(0.f, 0.f, 0.f, 0.f);
            if (n0 + c4 * 4 < NN)
                v = *reinterpret_cast<const float4*>(x + (size_t)row * NN + n0 + c4 * 4);
            *reinterpret_cast<float4*>(&xs[idx * 4]) = v;
        }
    }

    // ---- issue all W loads: 16 float4 in flight per thread ----
    float4 w0[8], w1[8];
    const float4* W0 = reinterpret_cast<const float4*>(W + ((size_t)nc * CH + og) * CH);
    const float4* W1 = reinterpret_cast<const float4*>(W + ((size_t)nc * CH + og + 16) * CH);
    #pragma unroll
    for (int k = 0; k < 8; ++k) w0[k] = W0[k];
    #pragma unroll
    for (int k = 0; k < 8; ++k) w1[k] = W1[k];
    const float b0 = bias[(size_t)nc * CH + og];
    const float b1 = bias[(size_t)nc * CH + og + 16];

    __syncthreads();                          // drains x->LDS (and W by vmcnt(0))
    __builtin_amdgcn_sched_barrier(0);        // forbid sinking W loads into compute

    // ---- compute: per thread one node, two out-channels, all batches ----
    #pragma unroll
    for (int b = 0; b < BATCH; ++b) {
        float a0 = b0, a1 = b1;
        const float* xb = &xs[(b * CH) * NT + nn];
        #pragma unroll
        for (int k = 0; k < 8; ++k) {
            const float* w0p = reinterpret_cast<const float*>(&w0[k]);
            const float* w1p = reinterpret_cast<const float*>(&w1[k]);
            #pragma unroll
            for (int j = 0; j < 4; ++j) {
                float xv = xb[(k * 4 + j) * NT];
                a0 = fmaf(w0p[j], xv, a0);
                a1 = fmaf(w1p[j], xv, a1);
            }
        }
        if (valid) {
            out[((size_t)b * CH + og) * NN + n]        = a0;
            out[((size_t)b * CH + og + 16) * NN + n]   = a1;
        }
    }
}

extern "C" void kernel_launch(void* const* d_in, const int* in_sizes, int n_in,
                              void* d_out, int out_size, void* d_ws, size_t ws_size,
                              hipStream_t stream) {
    const float* x    = (const float*)d_in[0];
    const float* W    = (const float*)d_in[1];
    const float* bias = (const float*)d_in[2];
    float* out        = (float*)d_out;

    const int blocks = (NN + NT - 1) / NT;   // 1563
    localconv1d_kernel<<<blocks, TPB, 0, stream>>>(x, W, bias, out);
}